// Round 4
// baseline (238.613 us; speedup 1.0000x reference)
//
#include <hip/hip_runtime.h>
#include <hip/hip_bf16.h>

#define BATCH   16384
#define NUM_IN  4096
#define NUM_OUT 1024
#define NNZ     262144
#define BN_EPS  1e-3f

typedef __attribute__((ext_vector_type(8)))  short short8;
typedef __attribute__((ext_vector_type(4)))  float f32x4;
typedef __attribute__((ext_vector_type(16))) float f32x16;
typedef __attribute__((ext_vector_type(4)))  unsigned int u32x4;

typedef __attribute__((address_space(3))) void        lds_void_t;
typedef const __attribute__((address_space(1))) void  g_void_t;

__device__ inline unsigned short f2bf(float f) {
    // round-to-nearest-even fp32 -> bf16 (off the hot path)
    unsigned int u = __builtin_bit_cast(unsigned int, f);
    u += 0x7fffu + ((u >> 16) & 1u);
    return (unsigned short)(u >> 16);
}

// ---------------- kernel 1: zero W_t (fp32, transposed [NUM_OUT][NUM_IN]) ----
__global__ void k_zero(f32x4* __restrict__ p) {
    p[(size_t)blockIdx.x * 256 + threadIdx.x] = f32x4{0.f, 0.f, 0.f, 0.f};
}

// ---------------- kernel 2: scatter-add sparse values into W_t --------------
__global__ void k_scatter(const float* __restrict__ v, const int* __restrict__ r,
                          const int* __restrict__ c, float* __restrict__ wtf) {
    int i = blockIdx.x * 256 + threadIdx.x;
    atomicAdd(&wtf[(size_t)c[i] * NUM_IN + r[i]], v[i]);
}

// ---------------- kernel 3: fold BN scale into W (bf16) + bias_out ----------
__global__ void k_wprep(const float* __restrict__ wtf, const float* __restrict__ gamma,
                        const float* __restrict__ beta, const float* __restrict__ mean,
                        const float* __restrict__ var, unsigned short* __restrict__ wtb,
                        float* __restrict__ bias) {
    const int n = blockIdx.x;
    const int t = threadIdx.x;
    float acc = 0.f;
    for (int k = t; k < NUM_IN; k += 256) {
        float w = wtf[(size_t)n * NUM_IN + k];
        float s = gamma[k] * rsqrtf(var[k] + BN_EPS);
        wtb[(size_t)n * NUM_IN + k] = f2bf(w * s);
        acc += (beta[k] - mean[k] * s) * w;
    }
    #pragma unroll
    for (int o = 32; o; o >>= 1) acc += __shfl_down(acc, o, 64);
    __shared__ float red[4];
    if ((t & 63) == 0) red[t >> 6] = acc;
    __syncthreads();
    if (t == 0) bias[n] = red[0] + red[1] + red[2] + red[3];
}

// ---------------- kernel 4: bf16 MFMA GEMM: out = x @ W'^T + bias -----------
// BM=BN=256, BK=32, 512 thr = 8 waves (2M x 4N), per-wave 128x64, MFMA 32x32x16.
// A: reg-staged fp32->bf16 (v_perm) -> ds_write (T14 split, 1-iter gap).
// B: global_load_lds direct. Ring-4 LDS (128 KB). Two sub-phases per K-tile,
// counted vmcnt(6) once per K-tile, setprio around MFMA clusters.
// LDS rows 64 B; XOR swizzle ((r>>1)&3)<<4 balances ds_read_b128 banks.
#define BM 256
#define BN 256
#define BK 32
#define NT (NUM_IN / BK)      /* 128 */
#define SLOT 32768            /* A 16 KB + B 16 KB */
#define B_OFF 16384

__global__ __launch_bounds__(512, 2) void k_gemm(const float* __restrict__ x,
                                                 const unsigned short* __restrict__ wt,
                                                 const float* __restrict__ bias,
                                                 float* __restrict__ out) {
    __shared__ __align__(128) char lds[4 * SLOT];

    // XCD swizzle: 256 blocks (1/CU); XCD x gets 8 m-panels x all 4 n-tiles.
    const int bid = blockIdx.x;
    const int swz = (bid & 7) * 32 + (bid >> 3);
    const int m0 = (swz >> 2) * BM;
    const int n0 = (swz & 3) * BN;

    const int t    = threadIdx.x;
    const int lane = t & 63;
    const int wid  = t >> 6;
    const int wm   = wid >> 2;        // 0..1 -> 128-row strip
    const int wn   = wid & 3;         // 0..3 -> 64-col strip

    const char* xb = (const char*)x;
    const char* wb = (const char*)wt;

    // staging geometry: A thread t -> row t>>1, k-half t&1 (16 fp32 -> 16 bf16)
    const int s_ar  = t >> 1;
    const int s_ah  = t & 1;
    const int a_swz = ((s_ar >> 1) & 3) << 4;
    // B gload_lds: issue i -> col i*128 + (t>>2), kbyte (t&3)*16 (pre-swizzled src)
    const int s_bc  = t >> 2;
    const int s_bk  = (t & 3) * 16;

    f32x4 rA[2][4];     // double-buffered A-staging regs (static-indexed)

    auto stageB = [&](int kt, int slot) {
        #pragma unroll
        for (int i = 0; i < 2; ++i) {
            int c = i * 128 + s_bc;
            size_t src = (size_t)(n0 + c) * (NUM_IN * 2) + kt * (BK * 2)
                       + (s_bk ^ (((c >> 1) & 3) << 4));
            __builtin_amdgcn_global_load_lds((g_void_t*)(wb + src),
                (lds_void_t*)(lds + slot * SLOT + B_OFF + i * 8192 + t * 16), 16, 0, 0);
        }
    };
    auto loadA = [&](int kt, int rs) {
        size_t src = (size_t)(m0 + s_ar) * (NUM_IN * 4) + kt * (BK * 4) + s_ah * 64;
        #pragma unroll
        for (int j = 0; j < 4; ++j)
            rA[rs][j] = *(const f32x4*)(xb + src + j * 16);
    };
    auto writeA = [&](int slot, int rs) {
        const unsigned int* f = (const unsigned int*)&rA[rs][0];
        u32x4 p0, p1;   // fp32 -> bf16 (RTZ) via v_perm
        p0[0] = __builtin_amdgcn_perm(f[1],  f[0],  0x07060302u);
        p0[1] = __builtin_amdgcn_perm(f[3],  f[2],  0x07060302u);
        p0[2] = __builtin_amdgcn_perm(f[5],  f[4],  0x07060302u);
        p0[3] = __builtin_amdgcn_perm(f[7],  f[6],  0x07060302u);
        p1[0] = __builtin_amdgcn_perm(f[9],  f[8],  0x07060302u);
        p1[1] = __builtin_amdgcn_perm(f[11], f[10], 0x07060302u);
        p1[2] = __builtin_amdgcn_perm(f[13], f[12], 0x07060302u);
        p1[3] = __builtin_amdgcn_perm(f[15], f[14], 0x07060302u);
        char* dst = lds + slot * SLOT + s_ar * 64;
        *(u32x4*)(dst + ((s_ah * 32 +  0) ^ a_swz)) = p0;
        *(u32x4*)(dst + ((s_ah * 32 + 16) ^ a_swz)) = p1;
    };

    // fragment geometry (32x32x16: lane -> row=lane&31, k-chunk=(lane>>5)*8)
    const int fa_row = wm * 128 + (lane & 31);
    const int fb_col = wn * 64 + (lane & 31);
    const int f_kb   = (lane >> 5) * 16;

    short8 afr[4], bfr[2];
    auto readFrags = [&](int slot, int q) {
        const char* A = lds + slot * SLOT;
        const char* B = A + B_OFF;
        #pragma unroll
        for (int m = 0; m < 4; ++m) {
            int row = fa_row + m * 32;
            afr[m] = *(const short8*)(A + row * 64
                       + ((q * 32 + f_kb) ^ (((row >> 1) & 3) << 4)));
        }
        #pragma unroll
        for (int n = 0; n < 2; ++n) {
            int col = fb_col + n * 32;
            bfr[n] = *(const short8*)(B + col * 64
                       + ((q * 32 + f_kb) ^ (((col >> 1) & 3) << 4)));
        }
    };

    f32x16 acc[4][2] = {};
    auto domfma = [&]() {
        __builtin_amdgcn_s_setprio(1);
        #pragma unroll
        for (int m = 0; m < 4; ++m)
            #pragma unroll
            for (int n = 0; n < 2; ++n)
                acc[m][n] = __builtin_amdgcn_mfma_f32_32x32x16_bf16(
                    afr[m], bfr[n], acc[m][n], 0, 0, 0);
        __builtin_amdgcn_s_setprio(0);
    };

    // body: consume tile kt (slot kt&3); stage tile kt+2; convert+write A(kt+1)
    auto body = [&](int kt, int rs, bool doStage, bool doConv, bool vm0) {
        const int cs = kt & 3;
        // ---- phase 0 (k-step 0) ----
        if (doStage) {
            stageB(kt + 2, (kt + 2) & 3);
            loadA(kt + 2, rs);
            __builtin_amdgcn_sched_barrier(0);
        }
        readFrags(cs, 0);
        asm volatile("s_waitcnt lgkmcnt(0)" ::: "memory");
        __builtin_amdgcn_sched_barrier(0);
        domfma();
        __builtin_amdgcn_s_barrier();
        // ---- phase 1 (k-step 1) ----
        readFrags(cs, 1);
        __builtin_amdgcn_sched_barrier(0);
        if (doConv) {
            if (vm0) asm volatile("s_waitcnt vmcnt(0)" ::: "memory");
            else     asm volatile("s_waitcnt vmcnt(6)" ::: "memory");
            writeA((kt + 1) & 3, rs ^ 1);
            asm volatile("s_waitcnt lgkmcnt(2)" ::: "memory");  // 6 reads done
        } else {
            asm volatile("s_waitcnt lgkmcnt(0)" ::: "memory");
        }
        __builtin_amdgcn_sched_barrier(0);
        domfma();
        asm volatile("s_waitcnt lgkmcnt(0)" ::: "memory");
        __builtin_amdgcn_s_barrier();
    };

    // prologue: stage tiles 0,1; convert A(0) now, A(1) in iter 0
    stageB(0, 0); loadA(0, 0);
    stageB(1, 1); loadA(1, 1);
    asm volatile("s_waitcnt vmcnt(6)" ::: "memory");   // A(0),B(0) landed
    writeA(0, 0);
    asm volatile("s_waitcnt lgkmcnt(0)" ::: "memory");
    __builtin_amdgcn_s_barrier();

    #pragma unroll 1
    for (int kt = 0; kt < NT - 2; kt += 2) {
        body(kt,     0, true, true, false);   // loads A(kt+2)->rA0, converts rA1
        body(kt + 1, 1, true, true, false);   // loads A(kt+3)->rA1, converts rA0
    }
    body(NT - 2, 0, false, true, true);       // converts A(127) from rA1, vmcnt(0)
    body(NT - 1, 1, false, false, false);     // pure compute

    // epilogue: 32x32 C/D layout: col=lane&31, row=(reg&3)+8*(reg>>2)+4*(lane>>5)
    float bj[2];
    #pragma unroll
    for (int n = 0; n < 2; ++n) bj[n] = bias[n0 + wn * 64 + n * 32 + (lane & 31)];
    const int rbase = m0 + wm * 128 + 4 * (lane >> 5);
    const int cbase = n0 + wn * 64 + (lane & 31);
    #pragma unroll
    for (int m = 0; m < 4; ++m)
        #pragma unroll
        for (int n = 0; n < 2; ++n)
            #pragma unroll
            for (int r = 0; r < 16; ++r) {
                int row = rbase + m * 32 + (r & 3) + 8 * (r >> 2);
                out[(size_t)row * NUM_OUT + cbase + n * 32] = acc[m][n][r] + bj[n];
            }
}

extern "C" void kernel_launch(void* const* d_in, const int* in_sizes, int n_in,
                              void* d_out, int out_size, void* d_ws, size_t ws_size,
                              hipStream_t stream) {
    const float* x     = (const float*)d_in[0];
    const float* spv   = (const float*)d_in[1];
    const float* gamma = (const float*)d_in[2];
    const float* beta  = (const float*)d_in[3];
    const float* mean  = (const float*)d_in[4];
    const float* var   = (const float*)d_in[5];
    const int*   rows  = (const int*)d_in[6];
    const int*   cols  = (const int*)d_in[7];
    float* out = (float*)d_out;

    // W_t fp32 scratch lives in d_out (dead before k_gemm overwrites it).
    float* wtf = (float*)d_out;
    unsigned short* wtb = (unsigned short*)d_ws;
    float* bias = (float*)((char*)d_ws + (size_t)NUM_IN * NUM_OUT * sizeof(unsigned short));

    hipLaunchKernelGGL(k_zero, dim3((NUM_IN * NUM_OUT / 4) / 256), dim3(256), 0, stream,
                       (f32x4*)wtf);
    hipLaunchKernelGGL(k_scatter, dim3(NNZ / 256), dim3(256), 0, stream,
                       spv, rows, cols, wtf);
    hipLaunchKernelGGL(k_wprep, dim3(NUM_OUT), dim3(256), 0, stream,
                       wtf, gamma, beta, mean, var, wtb, bias);
    hipLaunchKernelGGL(k_gemm, dim3((BATCH / BM) * (NUM_OUT / BN)), dim3(512), 0, stream,
                       x, wtb, bias, out);
}